// Round 1
// baseline (400.568 us; speedup 1.0000x reference)
//
#include <hip/hip_runtime.h>

typedef unsigned short u16;
typedef unsigned int   u32;
typedef __bf16 bf16x8 __attribute__((ext_vector_type(8)));
typedef float  f32x4  __attribute__((ext_vector_type(4)));
typedef u16    u16x4  __attribute__((ext_vector_type(4)));

#define DEV __device__ __forceinline__

DEV u16 f2bf(float f) {
    u32 u = __builtin_bit_cast(u32, f);
    u = (u + 0x7fffu + ((u >> 16) & 1u)) >> 16;
    return (u16)u;
}

DEV void gload16(const void* g, void* l) {
    __builtin_amdgcn_global_load_lds((const __attribute__((address_space(1))) u32*)g,
                                     (__attribute__((address_space(3))) u32*)l, 16, 0, 0);
}

// ---------------- conversion kernels ----------------

__global__ __launch_bounds__(256) void k_cvt4(const float* __restrict__ in,
                                              u16* __restrict__ out, int n) {
    int i = ((int)blockIdx.x * 256 + (int)threadIdx.x) * 4;
    if (i < n) {
        float4 v = *(const float4*)(in + i);
        u16x4 o;
        o[0] = f2bf(v.x); o[1] = f2bf(v.y); o[2] = f2bf(v.z); o[3] = f2bf(v.w);
        *(u16x4*)(out + i) = o;
    }
}

// wcatT[1536][512] = [wq|wk|wv]^T ; woT[512][512] = w_out^T  (both bf16, [N][K])
__global__ __launch_bounds__(256) void k_wt(const float* __restrict__ wq, const float* __restrict__ wk,
                                            const float* __restrict__ wv, const float* __restrict__ wo,
                                            u16* __restrict__ wcatT, u16* __restrict__ woT) {
    int idx = (int)blockIdx.x * 256 + (int)threadIdx.x;
    if (idx < 786432) {
        int j = idx >> 9, k = idx & 511;
        const float* w = (j < 512) ? wq : ((j < 1024) ? wk : wv);
        wcatT[idx] = f2bf(w[k * 512 + (j & 511)]);
    } else {
        int t = idx - 786432;
        int j = t >> 9, k = t & 511;
        woT[t] = f2bf(wo[k * 512 + j]);
    }
}

// E[h][n][r] f32 -> Et[h][r][n] bf16 (and F -> Ft). LDS-tiled 64x64 transpose.
__global__ __launch_bounds__(256) void k_tef(const float* __restrict__ E, const float* __restrict__ F,
                                             u16* __restrict__ Et, u16* __restrict__ Ft) {
    __shared__ u16 tile[64][65];
    const int t = threadIdx.x;
    const int bid = blockIdx.x;
    const int rt = bid & 3, ntl = (bid >> 2) & 63, h = (bid >> 8) & 7, which = bid >> 11;
    const float* src = (which ? F : E) + (size_t)h * 4096 * 256;
    u16* dst = (which ? Ft : Et) + (size_t)h * 256 * 4096;
    const int n0 = ntl * 64, r0 = rt * 64;
#pragma unroll
    for (int it = 0; it < 16; ++it) {
        const int idx = t + it * 256;
        const int nl = idx >> 6, rl = idx & 63;
        tile[nl][rl] = f2bf(src[(size_t)(n0 + nl) * 256 + r0 + rl]);
    }
    __syncthreads();
#pragma unroll
    for (int it = 0; it < 16; ++it) {
        const int idx = t + it * 256;
        const int rl = idx >> 6, nl = idx & 63;
        dst[(size_t)(r0 + rl) * 4096 + n0 + nl] = tile[nl][rl];
    }
}

// ---------------- tiled bf16 GEMM: C[M][N] = A[M][K] * B^T[N][K] ----------------
// MODE 0: QKV fused epilogue (Q natural layout, K/V transposed per head)
// MODE 1: fp32 out + bias
template <int MODE>
__global__ __launch_bounds__(256) void k_gemm(const u16* __restrict__ A, const u16* __restrict__ Bm,
                                              u16* __restrict__ Qo, u16* __restrict__ Kt, u16* __restrict__ Vt,
                                              float* __restrict__ Of, const float* __restrict__ bias,
                                              int M, int N, int K) {
    __shared__ __attribute__((aligned(16))) char smem[32768];
    const int tid = threadIdx.x;
    const int lane = tid & 63, wid = tid >> 6;
    const int wr = wid >> 1, wc = wid & 1;
    const int g = lane >> 4, l16 = lane & 15;
    const int nM = M >> 7;
    const int bm = (int)blockIdx.x % nM, bn = (int)blockIdx.x / nM;
    const int m0 = bm << 7, n0 = bn << 7;

    f32x4 acc[4][4] = {};

    for (int k0 = 0; k0 < K; k0 += 64) {
#pragma unroll
        for (int c = 0; c < 4; ++c) {
            const int off = c * 4096 + tid * 16;
            const int row = off >> 7;
            const int sc = ((off >> 4) & 7) ^ (row & 7);   // pre-swizzled global source
            gload16(A  + (size_t)(m0 + row) * K + (k0 + sc * 8), smem + off);
            gload16(Bm + (size_t)(n0 + row) * K + (k0 + sc * 8), smem + 16384 + off);
        }
        __syncthreads();
#pragma unroll
        for (int kk = 0; kk < 64; kk += 32) {
            bf16x8 av[4], bv[4];
#pragma unroll
            for (int m = 0; m < 4; ++m) {
                const int r = wr * 64 + m * 16 + l16;
                av[m] = *(const bf16x8*)(smem + r * 128 + ((kk * 2 + g * 16) ^ ((r & 7) << 4)));
            }
#pragma unroll
            for (int n = 0; n < 4; ++n) {
                const int r = wc * 64 + n * 16 + l16;
                bv[n] = *(const bf16x8*)(smem + 16384 + r * 128 + ((kk * 2 + g * 16) ^ ((r & 7) << 4)));
            }
#pragma unroll
            for (int m = 0; m < 4; ++m)
#pragma unroll
                for (int n = 0; n < 4; ++n)
                    acc[m][n] = __builtin_amdgcn_mfma_f32_16x16x32_bf16(av[m], bv[n], acc[m][n], 0, 0, 0);
        }
        __syncthreads();
    }

    if (MODE == 0) {
        if (n0 < 512) {  // Q section: natural [32768][512]
#pragma unroll
            for (int m = 0; m < 4; ++m)
#pragma unroll
                for (int n = 0; n < 4; ++n) {
                    const int col = n0 + wc * 64 + n * 16 + l16;
#pragma unroll
                    for (int i = 0; i < 4; ++i) {
                        const int row = m0 + wr * 64 + m * 16 + g * 4 + i;
                        Qo[(size_t)row * 512 + col] = f2bf(acc[m][n][i]);
                    }
                }
        } else {         // K/V: write transposed per head [b,h,d,n]
            u16* dst = (n0 < 1024) ? Kt : Vt;
#pragma unroll
            for (int m = 0; m < 4; ++m)
#pragma unroll
                for (int n = 0; n < 4; ++n) {
                    const int col = (n0 + wc * 64 + n * 16 + l16) & 511;
                    const int h = col >> 6, d = col & 63;
                    const int rowb = m0 + wr * 64 + m * 16 + g * 4;
                    const int b = rowb >> 12, nn = rowb & 4095;
                    u16x4 pk;
#pragma unroll
                    for (int i = 0; i < 4; ++i) pk[i] = f2bf(acc[m][n][i]);
                    *(u16x4*)(dst + ((size_t)((b * 8 + h) * 64 + d)) * 4096 + nn) = pk;
                }
        }
    } else {
#pragma unroll
        for (int m = 0; m < 4; ++m)
#pragma unroll
            for (int n = 0; n < 4; ++n) {
                const int col = n0 + wc * 64 + n * 16 + l16;
                const float bb = bias[col];
#pragma unroll
                for (int i = 0; i < 4; ++i) {
                    const int row = m0 + wr * 64 + m * 16 + g * 4 + i;
                    Of[(size_t)row * N + col] = acc[m][n][i] + bb;
                }
            }
    }
}

// ---------------- Linformer projections: kproj = E^T @ K_head, vproj = F^T @ V_head ----------------
// Per block: one 128-row (r) tile of one (b,h,which). K-dim = n = 4096.
__global__ __launch_bounds__(256) void k_proj(const u16* __restrict__ Et, const u16* __restrict__ Ft,
                                              const u16* __restrict__ Kt, const u16* __restrict__ Vt,
                                              u16* __restrict__ kp, u16* __restrict__ vpT) {
    __shared__ __attribute__((aligned(16))) char smem[24576];
    const int tid = threadIdx.x;
    const int lane = tid & 63, wid = tid >> 6;
    const int wr = wid >> 1, wc = wid & 1;
    const int g = lane >> 4, l16 = lane & 15;
    const int bid = blockIdx.x;
    const int mt = bid & 1, which = (bid >> 1) & 1, bh = bid >> 2;
    const int h = bh & 7;
    const u16* Ap = (which ? Ft : Et) + (size_t)h * 256 * 4096 + (size_t)mt * 128 * 4096;
    const u16* Bp = (which ? Vt : Kt) + (size_t)bh * 64 * 4096;

    f32x4 acc[4][2] = {};

    for (int k0 = 0; k0 < 4096; k0 += 64) {
#pragma unroll
        for (int c = 0; c < 4; ++c) {
            const int off = c * 4096 + tid * 16;
            const int row = off >> 7;
            const int sc = ((off >> 4) & 7) ^ (row & 7);
            gload16(Ap + (size_t)row * 4096 + (k0 + sc * 8), smem + off);
            if (c < 2)
                gload16(Bp + (size_t)row * 4096 + (k0 + sc * 8), smem + 16384 + off);
        }
        __syncthreads();
#pragma unroll
        for (int kk = 0; kk < 64; kk += 32) {
            bf16x8 av[4], bv[2];
#pragma unroll
            for (int m = 0; m < 4; ++m) {
                const int r = wr * 64 + m * 16 + l16;
                av[m] = *(const bf16x8*)(smem + r * 128 + ((kk * 2 + g * 16) ^ ((r & 7) << 4)));
            }
#pragma unroll
            for (int n = 0; n < 2; ++n) {
                const int r = wc * 32 + n * 16 + l16;
                bv[n] = *(const bf16x8*)(smem + 16384 + r * 128 + ((kk * 2 + g * 16) ^ ((r & 7) << 4)));
            }
#pragma unroll
            for (int m = 0; m < 4; ++m)
#pragma unroll
                for (int n = 0; n < 2; ++n)
                    acc[m][n] = __builtin_amdgcn_mfma_f32_16x16x32_bf16(av[m], bv[n], acc[m][n], 0, 0, 0);
        }
        __syncthreads();
    }

    if (which == 0) {  // kproj [bh][r=256][d=64] bf16
#pragma unroll
        for (int m = 0; m < 4; ++m)
#pragma unroll
            for (int n = 0; n < 2; ++n) {
                const int d = wc * 32 + n * 16 + l16;
#pragma unroll
                for (int i = 0; i < 4; ++i) {
                    const int rg = mt * 128 + wr * 64 + m * 16 + g * 4 + i;
                    kp[(size_t)bh * 16384 + rg * 64 + d] = f2bf(acc[m][n][i]);
                }
            }
    } else {           // vprojT [bh][d=64][r=256] bf16
#pragma unroll
        for (int m = 0; m < 4; ++m)
#pragma unroll
            for (int n = 0; n < 2; ++n) {
                const int d = wc * 32 + n * 16 + l16;
                const int r4 = mt * 128 + wr * 64 + m * 16 + g * 4;
                u16x4 pk;
#pragma unroll
                for (int i = 0; i < 4; ++i) pk[i] = f2bf(acc[m][n][i]);
                *(u16x4*)(vpT + (size_t)bh * 16384 + d * 256 + r4) = pk;
            }
    }
}

// ---------------- fused scores + softmax + PV ----------------
// Block: 64 q-rows of one (b,h); 4 waves x 16 rows. r=256 fully in registers.
__global__ __launch_bounds__(256) void k_flash(const u16* __restrict__ Q, const u16* __restrict__ kp,
                                               const u16* __restrict__ vpT, u16* __restrict__ ctx) {
    __shared__ __attribute__((aligned(16))) char smem[65536];  // [0,32K): kproj then P ; [32K,64K): vprojT
    const int tid = threadIdx.x;
    const int lane = tid & 63, w = tid >> 6;
    const int g = lane >> 4, l16 = lane & 15;
    const int bid = blockIdx.x;
    const int nt = bid & 63, bh = bid >> 6;
    const int b = bh >> 3, h = bh & 7;
    const int n0 = nt * 64;

    // stage kproj [256][64] (swizzled) and vprojT [64][256] (swizzled)
#pragma unroll
    for (int c = 0; c < 8; ++c) {
        const int off = c * 4096 + tid * 16;
        {
            const int row = off >> 7;
            const int sc = ((off >> 4) & 7) ^ (row & 7);
            gload16(kp + (size_t)bh * 16384 + row * 64 + sc * 8, smem + off);
        }
        {
            const int row = off >> 9;
            const int sc = ((off >> 4) & 31) ^ (row & 7);
            gload16(vpT + (size_t)bh * 16384 + row * 256 + sc * 8, smem + 32768 + off);
        }
    }
    // Q A-fragments straight from global (bf16, d-contiguous)
    const size_t qbase = (size_t)(b * 4096 + n0 + w * 16 + l16) * 512 + h * 64 + g * 8;
    bf16x8 qf0 = *(const bf16x8*)(Q + qbase);
    bf16x8 qf1 = *(const bf16x8*)(Q + qbase + 32);
    __syncthreads();

    // scores: S[n][r], 16 r-tiles
    f32x4 s[16];
#pragma unroll
    for (int rt = 0; rt < 16; ++rt) {
        const int r = rt * 16 + l16;
        const int sw = (r & 7) << 4;
        bf16x8 kv0 = *(const bf16x8*)(smem + r * 128 + ((g * 16) ^ sw));
        bf16x8 kv1 = *(const bf16x8*)(smem + r * 128 + ((64 + g * 16) ^ sw));
        f32x4 z = {0.f, 0.f, 0.f, 0.f};
        z = __builtin_amdgcn_mfma_f32_16x16x32_bf16(qf0, kv0, z, 0, 0, 0);
        z = __builtin_amdgcn_mfma_f32_16x16x32_bf16(qf1, kv1, z, 0, 0, 0);
        s[rt] = z;
    }

    // softmax over r (scale 1/sqrt(64)=0.125); rows live at (g,i), cols at l16 x rt
    float mx[4] = {-1e30f, -1e30f, -1e30f, -1e30f};
#pragma unroll
    for (int rt = 0; rt < 16; ++rt)
#pragma unroll
        for (int i = 0; i < 4; ++i) {
            s[rt][i] *= 0.125f;
            mx[i] = fmaxf(mx[i], s[rt][i]);
        }
#pragma unroll
    for (int i = 0; i < 4; ++i) {
        mx[i] = fmaxf(mx[i], __shfl_xor(mx[i], 1));
        mx[i] = fmaxf(mx[i], __shfl_xor(mx[i], 2));
        mx[i] = fmaxf(mx[i], __shfl_xor(mx[i], 4));
        mx[i] = fmaxf(mx[i], __shfl_xor(mx[i], 8));
    }
    float sm[4] = {0.f, 0.f, 0.f, 0.f};
#pragma unroll
    for (int rt = 0; rt < 16; ++rt)
#pragma unroll
        for (int i = 0; i < 4; ++i) {
            float e = __expf(s[rt][i] - mx[i]);
            s[rt][i] = e;
            sm[i] += e;
        }
#pragma unroll
    for (int i = 0; i < 4; ++i) {
        sm[i] += __shfl_xor(sm[i], 1);
        sm[i] += __shfl_xor(sm[i], 2);
        sm[i] += __shfl_xor(sm[i], 4);
        sm[i] += __shfl_xor(sm[i], 8);
    }

    __syncthreads();  // everyone done reading kproj -> reuse its LDS for P

    // write unnormalized P (bf16) to per-wave region [16][256], swizzled
#pragma unroll
    for (int rt = 0; rt < 16; ++rt)
#pragma unroll
        for (int i = 0; i < 4; ++i) {
            const int nrow = g * 4 + i;
            const int byte = w * 8192 + nrow * 512 + ((rt * 32 + l16 * 2) ^ ((nrow & 7) << 4));
            *(u16*)(smem + byte) = f2bf(s[rt][i]);
        }
    // same-wave LDS ops are in order: safe to read our own P back
    bf16x8 af[8];
#pragma unroll
    for (int ks = 0; ks < 8; ++ks) {
        const int byte = w * 8192 + l16 * 512 + ((ks * 64 + g * 16) ^ ((l16 & 7) << 4));
        af[ks] = *(const bf16x8*)(smem + byte);
    }
    f32x4 o[4] = {};
#pragma unroll
    for (int dt = 0; dt < 4; ++dt)
#pragma unroll
        for (int ks = 0; ks < 8; ++ks) {
            const int row = dt * 16 + l16;
            const int byte = 32768 + row * 512 + ((ks * 64 + g * 16) ^ ((row & 7) << 4));
            bf16x8 bv = *(const bf16x8*)(smem + byte);
            o[dt] = __builtin_amdgcn_mfma_f32_16x16x32_bf16(af[ks], bv, o[dt], 0, 0, 0);
        }
    float rinv[4];
#pragma unroll
    for (int i = 0; i < 4; ++i) rinv[i] = 1.0f / sm[i];
#pragma unroll
    for (int dt = 0; dt < 4; ++dt)
#pragma unroll
        for (int i = 0; i < 4; ++i) {
            const int row = b * 4096 + n0 + w * 16 + g * 4 + i;
            const int col = h * 64 + dt * 16 + l16;
            ctx[(size_t)row * 512 + col] = f2bf(o[dt][i] * rinv[i]);
        }
}

// ---------------- host launch ----------------

extern "C" void kernel_launch(void* const* d_in, const int* in_sizes, int n_in,
                              void* d_out, int out_size, void* d_ws, size_t ws_size,
                              hipStream_t stream) {
    const float* x  = (const float*)d_in[0];
    const float* wq = (const float*)d_in[1];
    const float* wk = (const float*)d_in[2];
    const float* wv = (const float*)d_in[3];
    const float* E  = (const float*)d_in[4];
    const float* F  = (const float*)d_in[5];
    const float* wo = (const float*)d_in[6];
    const float* bo = (const float*)d_in[7];
    float* out = (float*)d_out;
    u16* ws = (u16*)d_ws;

    // workspace layout (u16 units)
    u16* xb    = ws;                 // 16,777,216 : x bf16 (later reused as ctx)
    u16* Qm    = ws + 16777216;      // 16,777,216
    u16* Kt    = ws + 33554432;      // 16,777,216 : [b,h,d,n]
    u16* Vt    = ws + 50331648;      // 16,777,216 : [b,h,d,n]
    u16* Et    = ws + 67108864;      //  8,388,608 : [h,r,n]
    u16* Ft    = ws + 75497472;      //  8,388,608
    u16* wcatT = ws + 83886080;      //    786,432
    u16* woT   = ws + 84672512;      //    262,144
    u16* kpB   = ws + 84934656;      //  1,048,576 : [bh,r,d]
    u16* vpT   = ws + 85983232;      //  1,048,576 : [bh,d,r]
    u16* ctx   = xb;                 // reuse (x dead after QKV GEMM)

    k_cvt4<<<16384, 256, 0, stream>>>(x, xb, 16777216);
    k_wt<<<4096, 256, 0, stream>>>(wq, wk, wv, wo, wcatT, woT);
    k_tef<<<4096, 256, 0, stream>>>(E, F, Et, Ft);
    k_gemm<0><<<3072, 256, 0, stream>>>(xb, wcatT, Qm, Kt, Vt, nullptr, nullptr, 32768, 1536, 512);
    k_proj<<<256, 256, 0, stream>>>(Et, Ft, Kt, Vt, kpB, vpT);
    k_flash<<<4096, 256, 0, stream>>>(Qm, kpB, vpT, ctx);
    k_gemm<1><<<1024, 256, 0, stream>>>(ctx, woT, nullptr, nullptr, nullptr, out, bo, 32768, 512, 512);
}

// Round 3
// 385.324 us; speedup vs baseline: 1.0396x; 1.0396x over previous
//
#include <hip/hip_runtime.h>

typedef unsigned short u16;
typedef unsigned int   u32;
typedef __bf16 bf16x8 __attribute__((ext_vector_type(8)));
typedef float  f32x4  __attribute__((ext_vector_type(4)));
typedef u16    u16x4  __attribute__((ext_vector_type(4)));

#define DEV __device__ __forceinline__

DEV u16 f2bf(float f) {
    u32 u = __builtin_bit_cast(u32, f);
    u = (u + 0x7fffu + ((u >> 16) & 1u)) >> 16;
    return (u16)u;
}

DEV void gload16(const void* g, void* l) {
    __builtin_amdgcn_global_load_lds((const __attribute__((address_space(1))) u32*)g,
                                     (__attribute__((address_space(3))) u32*)l, 16, 0, 0);
}

// ---------------- merged prep: x->bf16 | E/F transpose | W transposes ----------------
// grid = 16384 (cvt) + 4096 (tef) + 256 (wt) = 20736 blocks of 256
__global__ __launch_bounds__(256) void k_prep(const float* __restrict__ x,
                                              const float* __restrict__ wq, const float* __restrict__ wk,
                                              const float* __restrict__ wv, const float* __restrict__ wo,
                                              const float* __restrict__ E, const float* __restrict__ F,
                                              u16* __restrict__ xb, u16* __restrict__ wcatT, u16* __restrict__ woT,
                                              u16* __restrict__ Et, u16* __restrict__ Ft) {
    __shared__ u16 tile[64][65];
    const int t = threadIdx.x;
    const int bid = blockIdx.x;
    if (bid < 16384) {                       // x fp32 -> bf16
        int i = (bid * 256 + t) * 4;
        float4 v = *(const float4*)(x + i);
        u16x4 o;
        o[0] = f2bf(v.x); o[1] = f2bf(v.y); o[2] = f2bf(v.z); o[3] = f2bf(v.w);
        *(u16x4*)(xb + i) = o;
    } else if (bid < 20480) {                // E/F [h][n][r] -> [h][r][n] bf16, 64x64 LDS tiles
        const int b2 = bid - 16384;
        const int rt = b2 & 3, ntl = (b2 >> 2) & 63, h = (b2 >> 8) & 7, which = b2 >> 11;
        const float* src = (which ? F : E) + (size_t)h * 4096 * 256;
        u16* dst = (which ? Ft : Et) + (size_t)h * 256 * 4096;
        const int n0 = ntl * 64, r0 = rt * 64;
#pragma unroll
        for (int it = 0; it < 16; ++it) {
            const int idx = t + it * 256;
            const int nl = idx >> 6, rl = idx & 63;
            tile[nl][rl] = f2bf(src[(size_t)(n0 + nl) * 256 + r0 + rl]);
        }
        __syncthreads();
#pragma unroll
        for (int it = 0; it < 16; ++it) {
            const int idx = t + it * 256;
            const int rl = idx >> 6, nl = idx & 63;
            dst[(size_t)(r0 + rl) * 4096 + n0 + nl] = tile[nl][rl];
        }
    } else {                                 // W transposes, 64x64 LDS tiles
        const int b2 = bid - 20480;          // 0..255 : 4 matrices x 64 tiles
        const int mi = b2 >> 6, tix = b2 & 63;
        const int jt = tix & 7, kt = tix >> 3;
        const float* w = (mi == 0) ? wq : (mi == 1) ? wk : (mi == 2) ? wv : wo;
        u16* dst = (mi < 3) ? (wcatT + mi * 262144) : woT;
#pragma unroll
        for (int it = 0; it < 16; ++it) {
            const int idx = t + it * 256;
            const int kl = idx >> 6, jl = idx & 63;
            tile[kl][jl] = f2bf(w[(kt * 64 + kl) * 512 + jt * 64 + jl]);
        }
        __syncthreads();
#pragma unroll
        for (int it = 0; it < 16; ++it) {
            const int idx = t + it * 256;
            const int jl = idx >> 6, kl = idx & 63;
            dst[(size_t)(jt * 64 + jl) * 512 + kt * 64 + kl] = tile[kl][jl];
        }
    }
}

// ---------------- tiled bf16 GEMM: C[M][N] = A[M][K] * B^T[N][K] ----------------
// XCD-chunked swizzle: each XCD owns a 32-m-tile band, bm fast / bn slow.
// MODE 0: QKV fused epilogue (Q natural, K/V transposed per head); MODE 1: fp32 + bias
template <int MODE>
__global__ __launch_bounds__(256) void k_gemm(const u16* __restrict__ A, const u16* __restrict__ Bm,
                                              u16* __restrict__ Qo, u16* __restrict__ Kt, u16* __restrict__ Vt,
                                              float* __restrict__ Of, const float* __restrict__ bias,
                                              int M, int N, int K) {
    __shared__ __attribute__((aligned(16))) char smem[32768];
    const int tid = threadIdx.x;
    const int lane = tid & 63, wid = tid >> 6;
    const int wr = wid >> 1, wc = wid & 1;
    const int g = lane >> 4, l16 = lane & 15;
    const int bid = (int)blockIdx.x;
    const int xcd = bid & 7, loc = bid >> 3;
    const int bm = xcd * 32 + (loc & 31), bn = loc >> 5;
    const int m0 = bm << 7, n0 = bn << 7;

    f32x4 acc[4][4] = {};

    for (int k0 = 0; k0 < K; k0 += 64) {
#pragma unroll
        for (int c = 0; c < 4; ++c) {
            const int off = c * 4096 + tid * 16;
            const int row = off >> 7;
            const int sc = ((off >> 4) & 7) ^ (row & 7);   // pre-swizzled global source
            gload16(A  + (size_t)(m0 + row) * K + (k0 + sc * 8), smem + off);
            gload16(Bm + (size_t)(n0 + row) * K + (k0 + sc * 8), smem + 16384 + off);
        }
        __syncthreads();
#pragma unroll
        for (int kk = 0; kk < 64; kk += 32) {
            bf16x8 av[4], bv[4];
#pragma unroll
            for (int m = 0; m < 4; ++m) {
                const int r = wr * 64 + m * 16 + l16;
                av[m] = *(const bf16x8*)(smem + r * 128 + ((kk * 2 + g * 16) ^ ((r & 7) << 4)));
            }
#pragma unroll
            for (int n = 0; n < 4; ++n) {
                const int r = wc * 64 + n * 16 + l16;
                bv[n] = *(const bf16x8*)(smem + 16384 + r * 128 + ((kk * 2 + g * 16) ^ ((r & 7) << 4)));
            }
            __builtin_amdgcn_s_setprio(1);
#pragma unroll
            for (int m = 0; m < 4; ++m)
#pragma unroll
                for (int n = 0; n < 4; ++n)
                    acc[m][n] = __builtin_amdgcn_mfma_f32_16x16x32_bf16(av[m], bv[n], acc[m][n], 0, 0, 0);
            __builtin_amdgcn_s_setprio(0);
        }
        __syncthreads();
    }

    if (MODE == 0) {
        if (n0 < 512) {  // Q section: natural [32768][512]
#pragma unroll
            for (int m = 0; m < 4; ++m)
#pragma unroll
                for (int n = 0; n < 4; ++n) {
                    const int col = n0 + wc * 64 + n * 16 + l16;
#pragma unroll
                    for (int i = 0; i < 4; ++i) {
                        const int row = m0 + wr * 64 + m * 16 + g * 4 + i;
                        Qo[(size_t)row * 512 + col] = f2bf(acc[m][n][i]);
                    }
                }
        } else {         // K/V: write transposed per head [b,h,d,n]
            u16* dst = (n0 < 1024) ? Kt : Vt;
#pragma unroll
            for (int m = 0; m < 4; ++m)
#pragma unroll
                for (int n = 0; n < 4; ++n) {
                    const int col = (n0 + wc * 64 + n * 16 + l16) & 511;
                    const int h = col >> 6, d = col & 63;
                    const int rowb = m0 + wr * 64 + m * 16 + g * 4;
                    const int b = rowb >> 12, nn = rowb & 4095;
                    u16x4 pk;
#pragma unroll
                    for (int i = 0; i < 4; ++i) pk[i] = f2bf(acc[m][n][i]);
                    *(u16x4*)(dst + ((size_t)((b * 8 + h) * 64 + d)) * 4096 + nn) = pk;
                }
        }
    } else {
#pragma unroll
        for (int m = 0; m < 4; ++m)
#pragma unroll
            for (int n = 0; n < 4; ++n) {
                const int col = n0 + wc * 64 + n * 16 + l16;
                const float bb = bias[col];
#pragma unroll
                for (int i = 0; i < 4; ++i) {
                    const int row = m0 + wr * 64 + m * 16 + g * 4 + i;
                    Of[(size_t)row * N + col] = acc[m][n][i] + bb;
                }
            }
    }
}

// ---------------- Linformer projections, split-K x4 ----------------
// grid 1024: bid = sp*256 + (bh*4 + which*2 + mt). fp32 partials into pbuf.
__global__ __launch_bounds__(256) void k_proj(const u16* __restrict__ Et, const u16* __restrict__ Ft,
                                              const u16* __restrict__ Kt, const u16* __restrict__ Vt,
                                              float* __restrict__ pbuf) {
    __shared__ __attribute__((aligned(16))) char smem[24576];
    const int tid = threadIdx.x;
    const int lane = tid & 63, wid = tid >> 6;
    const int wr = wid >> 1, wc = wid & 1;
    const int g = lane >> 4, l16 = lane & 15;
    const int bid = blockIdx.x;
    const int sp = bid >> 8, rest = bid & 255;
    const int mt = rest & 1, which = (rest >> 1) & 1, bh = rest >> 2;
    const int h = bh & 7;
    const u16* Ap = (which ? Ft : Et) + (size_t)h * 256 * 4096 + (size_t)mt * 128 * 4096;
    const u16* Bp = (which ? Vt : Kt) + (size_t)bh * 64 * 4096;

    f32x4 acc[4][2] = {};

    const int kbeg = sp * 1024;
    for (int k0 = kbeg; k0 < kbeg + 1024; k0 += 64) {
#pragma unroll
        for (int c = 0; c < 4; ++c) {
            const int off = c * 4096 + tid * 16;
            const int row = off >> 7;
            const int sc = ((off >> 4) & 7) ^ (row & 7);
            gload16(Ap + (size_t)row * 4096 + (k0 + sc * 8), smem + off);
            if (c < 2)
                gload16(Bp + (size_t)row * 4096 + (k0 + sc * 8), smem + 16384 + off);
        }
        __syncthreads();
#pragma unroll
        for (int kk = 0; kk < 64; kk += 32) {
            bf16x8 av[4], bv[2];
#pragma unroll
            for (int m = 0; m < 4; ++m) {
                const int r = wr * 64 + m * 16 + l16;
                av[m] = *(const bf16x8*)(smem + r * 128 + ((kk * 2 + g * 16) ^ ((r & 7) << 4)));
            }
#pragma unroll
            for (int n = 0; n < 2; ++n) {
                const int r = wc * 32 + n * 16 + l16;
                bv[n] = *(const bf16x8*)(smem + 16384 + r * 128 + ((kk * 2 + g * 16) ^ ((r & 7) << 4)));
            }
            __builtin_amdgcn_s_setprio(1);
#pragma unroll
            for (int m = 0; m < 4; ++m)
#pragma unroll
                for (int n = 0; n < 2; ++n)
                    acc[m][n] = __builtin_amdgcn_mfma_f32_16x16x32_bf16(av[m], bv[n], acc[m][n], 0, 0, 0);
            __builtin_amdgcn_s_setprio(0);
        }
        __syncthreads();
    }

    float* pb = pbuf + ((size_t)(sp * 2 + which) * 64 + bh) * 16384;
    if (which == 0) {  // kp-partial [r=256][d=64]
#pragma unroll
        for (int m = 0; m < 4; ++m)
#pragma unroll
            for (int n = 0; n < 2; ++n) {
                const int d = wc * 32 + n * 16 + l16;
#pragma unroll
                for (int i = 0; i < 4; ++i) {
                    const int rg = mt * 128 + wr * 64 + m * 16 + g * 4 + i;
                    pb[rg * 64 + d] = acc[m][n][i];
                }
            }
    } else {           // vpT-partial [d=64][r=256]
#pragma unroll
        for (int m = 0; m < 4; ++m)
#pragma unroll
            for (int n = 0; n < 2; ++n) {
                const int d = wc * 32 + n * 16 + l16;
                const int r4 = mt * 128 + wr * 64 + m * 16 + g * 4;
                *(f32x4*)(pb + d * 256 + r4) = acc[m][n];
            }
    }
}

// reduce 4 split-K partials -> bf16 (kpB and vpT are contiguous: one 2.1M-elem array)
__global__ __launch_bounds__(256) void k_preduce(const float* __restrict__ pbuf, u16* __restrict__ outkv) {
    const int o = ((int)blockIdx.x * 256 + (int)threadIdx.x) * 4;
    f32x4 s = *(const f32x4*)(pbuf + o);
    s += *(const f32x4*)(pbuf + 2097152 + o);
    s += *(const f32x4*)(pbuf + 4194304 + o);
    s += *(const f32x4*)(pbuf + 6291456 + o);
    u16x4 r;
#pragma unroll
    for (int i = 0; i < 4; ++i) r[i] = f2bf(s[i]);
    *(u16x4*)(outkv + o) = r;
}

// ---------------- fused scores + softmax + PV ----------------
__global__ __launch_bounds__(256) void k_flash(const u16* __restrict__ Q, const u16* __restrict__ kp,
                                               const u16* __restrict__ vpT, u16* __restrict__ ctx) {
    __shared__ __attribute__((aligned(16))) char smem[65536];  // [0,32K): kproj then P ; [32K,64K): vprojT
    const int tid = threadIdx.x;
    const int lane = tid & 63, w = tid >> 6;
    const int g = lane >> 4, l16 = lane & 15;
    const int bid = blockIdx.x;
    const int nt = bid & 63, bh = bid >> 6;
    const int b = bh >> 3, h = bh & 7;
    const int n0 = nt * 64;

#pragma unroll
    for (int c = 0; c < 8; ++c) {
        const int off = c * 4096 + tid * 16;
        {
            const int row = off >> 7;
            const int sc = ((off >> 4) & 7) ^ (row & 7);
            gload16(kp + (size_t)bh * 16384 + row * 64 + sc * 8, smem + off);
        }
        {
            const int row = off >> 9;
            const int sc = ((off >> 4) & 31) ^ (row & 7);
            gload16(vpT + (size_t)bh * 16384 + row * 256 + sc * 8, smem + 32768 + off);
        }
    }
    const size_t qbase = (size_t)(b * 4096 + n0 + w * 16 + l16) * 512 + h * 64 + g * 8;
    bf16x8 qf0 = *(const bf16x8*)(Q + qbase);
    bf16x8 qf1 = *(const bf16x8*)(Q + qbase + 32);
    __syncthreads();

    // scores: S[n][r], 16 r-tiles
    f32x4 s[16];
    __builtin_amdgcn_s_setprio(1);
#pragma unroll
    for (int rt = 0; rt < 16; ++rt) {
        const int r = rt * 16 + l16;
        const int sw = (r & 7) << 4;
        bf16x8 kv0 = *(const bf16x8*)(smem + r * 128 + ((g * 16) ^ sw));
        bf16x8 kv1 = *(const bf16x8*)(smem + r * 128 + ((64 + g * 16) ^ sw));
        f32x4 z = {0.f, 0.f, 0.f, 0.f};
        z = __builtin_amdgcn_mfma_f32_16x16x32_bf16(qf0, kv0, z, 0, 0, 0);
        z = __builtin_amdgcn_mfma_f32_16x16x32_bf16(qf1, kv1, z, 0, 0, 0);
        s[rt] = z;
    }
    __builtin_amdgcn_s_setprio(0);

    // softmax over r (scale 0.125)
    float mx[4] = {-1e30f, -1e30f, -1e30f, -1e30f};
#pragma unroll
    for (int rt = 0; rt < 16; ++rt)
#pragma unroll
        for (int i = 0; i < 4; ++i) {
            s[rt][i] *= 0.125f;
            mx[i] = fmaxf(mx[i], s[rt][i]);
        }
#pragma unroll
    for (int i = 0; i < 4; ++i) {
        mx[i] = fmaxf(mx[i], __shfl_xor(mx[i], 1));
        mx[i] = fmaxf(mx[i], __shfl_xor(mx[i], 2));
        mx[i] = fmaxf(mx[i], __shfl_xor(mx[i], 4));
        mx[i] = fmaxf(mx[i], __shfl_xor(mx[i], 8));
    }
    float sm[4] = {0.f, 0.f, 0.f, 0.f};
#pragma unroll
    for (int rt = 0; rt < 16; ++rt)
#pragma unroll
        for (int i = 0; i < 4; ++i) {
            float e = __expf(s[rt][i] - mx[i]);
            s[rt][i] = e;
            sm[i] += e;
        }
#pragma unroll
    for (int i = 0; i < 4; ++i) {
        sm[i] += __shfl_xor(sm[i], 1);
        sm[i] += __shfl_xor(sm[i], 2);
        sm[i] += __shfl_xor(sm[i], 4);
        sm[i] += __shfl_xor(sm[i], 8);
    }

    __syncthreads();  // kproj reads done -> reuse LDS for P

    // unnormalized P (bf16) to per-wave region [16][256], swizzled
#pragma unroll
    for (int rt = 0; rt < 16; ++rt)
#pragma unroll
        for (int i = 0; i < 4; ++i) {
            const int nrow = g * 4 + i;
            const int byte = w * 8192 + nrow * 512 + ((rt * 32 + l16 * 2) ^ ((nrow & 7) << 4));
            *(u16*)(smem + byte) = f2bf(s[rt][i]);
        }
    bf16x8 af[8];
#pragma unroll
    for (int ks = 0; ks < 8; ++ks) {
        const int byte = w * 8192 + l16 * 512 + ((ks * 64 + g * 16) ^ ((l16 & 7) << 4));
        af[ks] = *(const bf16x8*)(smem + byte);
    }
    f32x4 o[4] = {};
    __builtin_amdgcn_s_setprio(1);
#pragma unroll
    for (int dt = 0; dt < 4; ++dt)
#pragma unroll
        for (int ks = 0; ks < 8; ++ks) {
            const int row = dt * 16 + l16;
            const int byte = 32768 + row * 512 + ((ks * 64 + g * 16) ^ ((row & 7) << 4));
            bf16x8 bv = *(const bf16x8*)(smem + byte);
            o[dt] = __builtin_amdgcn_mfma_f32_16x16x32_bf16(af[ks], bv, o[dt], 0, 0, 0);
        }
    __builtin_amdgcn_s_setprio(0);
    float rinv[4];
#pragma unroll
    for (int i = 0; i < 4; ++i) rinv[i] = 1.0f / sm[i];
#pragma unroll
    for (int dt = 0; dt < 4; ++dt)
#pragma unroll
        for (int i = 0; i < 4; ++i) {
            const int row = b * 4096 + n0 + w * 16 + g * 4 + i;
            const int col = h * 64 + dt * 16 + l16;
            ctx[(size_t)row * 512 + col] = f2bf(o[dt][i] * rinv[i]);
        }
}

// ---------------- host launch ----------------

extern "C" void kernel_launch(void* const* d_in, const int* in_sizes, int n_in,
                              void* d_out, int out_size, void* d_ws, size_t ws_size,
                              hipStream_t stream) {
    const float* x  = (const float*)d_in[0];
    const float* wq = (const float*)d_in[1];
    const float* wk = (const float*)d_in[2];
    const float* wv = (const float*)d_in[3];
    const float* E  = (const float*)d_in[4];
    const float* F  = (const float*)d_in[5];
    const float* wo = (const float*)d_in[6];
    const float* bo = (const float*)d_in[7];
    float* out = (float*)d_out;
    u16* ws = (u16*)d_ws;

    // workspace layout (u16 units)
    u16* xb    = ws;                 // 16,777,216 : x bf16 -> later proj partials (f32) -> later ctx
    u16* Qm    = ws + 16777216;
    u16* Kt    = ws + 33554432;      // [b,h,d,n]
    u16* Vt    = ws + 50331648;      // [b,h,d,n]
    u16* Et    = ws + 67108864;      // [h,r,n]
    u16* Ft    = ws + 75497472;
    u16* wcatT = ws + 83886080;
    u16* woT   = ws + 84672512;
    u16* kpB   = ws + 84934656;      // [bh,r,d]  (kpB and vpT contiguous!)
    u16* vpT   = ws + 85983232;      // [bh,d,r]
    float* pbuf = (float*)xb;        // 33.5 MB split-K partials (x-bf16 dead by then)
    u16* ctx   = xb;                 // reuse after preduce

    k_prep<<<20736, 256, 0, stream>>>(x, wq, wk, wv, wo, E, F, xb, wcatT, woT, Et, Ft);
    k_gemm<0><<<3072, 256, 0, stream>>>(xb, wcatT, Qm, Kt, Vt, nullptr, nullptr, 32768, 1536, 512);
    k_proj<<<1024, 256, 0, stream>>>(Et, Ft, Kt, Vt, pbuf);
    k_preduce<<<2048, 256, 0, stream>>>(pbuf, kpB);
    k_flash<<<4096, 256, 0, stream>>>(Qm, kpB, vpT, ctx);
    k_gemm<1><<<1024, 256, 0, stream>>>(ctx, woT, nullptr, nullptr, nullptr, out, bo, 32768, 512, 512);
}

// Round 4
// 379.617 us; speedup vs baseline: 1.0552x; 1.0150x over previous
//
#include <hip/hip_runtime.h>

typedef unsigned short u16;
typedef unsigned int   u32;
typedef __bf16 bf16x8 __attribute__((ext_vector_type(8)));
typedef float  f32x4  __attribute__((ext_vector_type(4)));
typedef u16    u16x4  __attribute__((ext_vector_type(4)));

#define DEV __device__ __forceinline__

DEV u16 f2bf(float f) {
    u32 u = __builtin_bit_cast(u32, f);
    u = (u + 0x7fffu + ((u >> 16) & 1u)) >> 16;
    return (u16)u;
}

DEV void gload16(const void* g, void* l) {
    __builtin_amdgcn_global_load_lds((const __attribute__((address_space(1))) u32*)g,
                                     (__attribute__((address_space(3))) u32*)l, 16, 0, 0);
}

DEV void vmw(int n) {  // counted vmcnt wait (literal required in asm)
    switch (n) {
        case 0:  asm volatile("s_waitcnt vmcnt(0)" ::: "memory"); break;
        case 4:  asm volatile("s_waitcnt vmcnt(4)" ::: "memory"); break;
        case 8:  asm volatile("s_waitcnt vmcnt(8)" ::: "memory"); break;
        default: asm volatile("s_waitcnt vmcnt(10)" ::: "memory"); break;
    }
}

// ---------------- merged prep: x->bf16 | E/F transpose | W transposes ----------------
__global__ __launch_bounds__(256) void k_prep(const float* __restrict__ x,
                                              const float* __restrict__ wq, const float* __restrict__ wk,
                                              const float* __restrict__ wv, const float* __restrict__ wo,
                                              const float* __restrict__ E, const float* __restrict__ F,
                                              u16* __restrict__ xb, u16* __restrict__ wcatT, u16* __restrict__ woT,
                                              u16* __restrict__ Et, u16* __restrict__ Ft) {
    __shared__ u16 tile[64][65];
    const int t = threadIdx.x;
    const int bid = blockIdx.x;
    if (bid < 16384) {                       // x fp32 -> bf16
        int i = (bid * 256 + t) * 4;
        float4 v = *(const float4*)(x + i);
        u16x4 o;
        o[0] = f2bf(v.x); o[1] = f2bf(v.y); o[2] = f2bf(v.z); o[3] = f2bf(v.w);
        *(u16x4*)(xb + i) = o;
    } else if (bid < 20480) {                // E/F [h][n][r] -> [h][r][n] bf16
        const int b2 = bid - 16384;
        const int rt = b2 & 3, ntl = (b2 >> 2) & 63, h = (b2 >> 8) & 7, which = b2 >> 11;
        const float* src = (which ? F : E) + (size_t)h * 4096 * 256;
        u16* dst = (which ? Ft : Et) + (size_t)h * 256 * 4096;
        const int n0 = ntl * 64, r0 = rt * 64;
#pragma unroll
        for (int it = 0; it < 16; ++it) {
            const int idx = t + it * 256;
            const int nl = idx >> 6, rl = idx & 63;
            tile[nl][rl] = f2bf(src[(size_t)(n0 + nl) * 256 + r0 + rl]);
        }
        __syncthreads();
#pragma unroll
        for (int it = 0; it < 16; ++it) {
            const int idx = t + it * 256;
            const int rl = idx >> 6, nl = idx & 63;
            dst[(size_t)(r0 + rl) * 4096 + n0 + nl] = tile[nl][rl];
        }
    } else {                                 // W transposes
        const int b2 = bid - 20480;
        const int mi = b2 >> 6, tix = b2 & 63;
        const int jt = tix & 7, kt = tix >> 3;
        const float* w = (mi == 0) ? wq : (mi == 1) ? wk : (mi == 2) ? wv : wo;
        u16* dst = (mi < 3) ? (wcatT + mi * 262144) : woT;
#pragma unroll
        for (int it = 0; it < 16; ++it) {
            const int idx = t + it * 256;
            const int kl = idx >> 6, jl = idx & 63;
            tile[kl][jl] = f2bf(w[(kt * 64 + kl) * 512 + jt * 64 + jl]);
        }
        __syncthreads();
#pragma unroll
        for (int it = 0; it < 16; ++it) {
            const int idx = t + it * 256;
            const int jl = idx >> 6, kl = idx & 63;
            dst[(size_t)(jt * 64 + jl) * 512 + kt * 64 + kl] = tile[kl][jl];
        }
    }
}

// ---------------- 8-phase 256x256 bf16 GEMM: C[M][N] = A[M][K] * B^T[N][K] ----------------
// 512 thr / 8 waves (2x4), per-wave C = 128x64. BK=64 split in 2 k-halves.
// LDS = 8 rotating 16KB half-tiles: A[4 slots] @0, B[4 slots] @64K.
// half-tile h = 4*ktile + {0:A-kh0, 1:B-kh0, 2:A-kh1, 3:B-kh1}; slot = (2*ktile+kh)&3.
// Phase (kt,s): kh=s>>1, nh=s&1; stages h = 4*kt+s+6; counted vmcnt per derivation.
template <int MODE>
__global__ __launch_bounds__(512, 2) void k_gemm8(const u16* __restrict__ A, const u16* __restrict__ Bm,
                                                  u16* __restrict__ Qo, u16* __restrict__ Kt, u16* __restrict__ Vt,
                                                  float* __restrict__ Of, const float* __restrict__ bias,
                                                  int M, int N, int K) {
    __shared__ __attribute__((aligned(16))) char smem[131072];
    const int tid = threadIdx.x;
    const int lane = tid & 63, w = tid >> 6;
    const int wr = w >> 2, wcn = w & 3;
    const int g = lane >> 4, l16 = lane & 15;
    const int nbm = M >> 8;
    const int total = nbm * (N >> 8);
    const int chunk = total >> 3;
    const int bid = (int)blockIdx.x;
    const int tt = (bid & 7) * chunk + (bid >> 3);   // XCD-chunked, bm-fast
    const int bm = tt % nbm, bn = tt / nbm;
    const int m0 = bm << 8, n0 = bn << 8;
    const int NT = K >> 6;

    auto stage_h = [&](int h) {
        const int ktile = h >> 2, ty = h & 3;
        const int kh = ty >> 1;
        const int isB = ty & 1;
        const int slot = (ktile * 2 + kh) & 3;
        const u16* src = isB ? Bm : A;
        const int r0 = isB ? n0 : m0;
        char* base = smem + isB * 65536 + slot * 16384;
#pragma unroll
        for (int j = 0; j < 2; ++j) {
            const int off = j * 8192 + tid * 16;
            const int row = off >> 6, c = (off >> 4) & 3;
            const int sc = c ^ ((row >> 1) & 3);        // pre-swizzled source -> swizzled LDS reads
            gload16(src + (size_t)(r0 + row) * K + ktile * 64 + kh * 32 + sc * 8, base + off);
        }
    };

    for (int h = 0; h < 6; ++h) stage_h(h);
    vmw(8);                                   // oldest 4 loads (h0,h1) landed
    __builtin_amdgcn_sched_barrier(0);
    __builtin_amdgcn_s_barrier();

    f32x4 acc[8][4] = {};
    bf16x8 av[8];
    for (int kt = 0; kt < NT; ++kt) {
#pragma unroll
        for (int s = 0; s < 4; ++s) {
            const int kh = s >> 1, nh = s & 1;
            const int slot = (kt * 2 + kh) & 3;
            char* abase = smem + slot * 16384;
            char* bbase = smem + 65536 + slot * 16384;
            if (nh == 0) {
#pragma unroll
                for (int m = 0; m < 8; ++m) {
                    const int row = wr * 128 + m * 16 + l16;
                    const int c = g ^ ((row >> 1) & 3);
                    av[m] = *(const bf16x8*)(abase + row * 64 + c * 16);
                }
            }
            bf16x8 bv[2];
#pragma unroll
            for (int n = 0; n < 2; ++n) {
                const int col = wcn * 64 + nh * 32 + n * 16 + l16;
                const int c = g ^ ((col >> 1) & 3);
                bv[n] = *(const bf16x8*)(bbase + col * 64 + c * 16);
            }
            const int hst = kt * 4 + s + 6;
            if (hst < NT * 4) stage_h(hst);
            __builtin_amdgcn_s_setprio(1);
#pragma unroll
            for (int m = 0; m < 8; ++m)
#pragma unroll
                for (int n = 0; n < 2; ++n)
                    acc[m][nh * 2 + n] = __builtin_amdgcn_mfma_f32_16x16x32_bf16(av[m], bv[n], acc[m][nh * 2 + n], 0, 0, 0);
            __builtin_amdgcn_s_setprio(0);
            const bool last = (kt == NT - 1) && (s == 3);
            if (!last) {
                int n;
                if (s == 0)      n = (kt < NT - 1) ? 10 : 4;
                else if (s == 1) n = (kt < NT - 1) ? 8 : 0;
                else if (s == 2) n = (kt < NT - 2) ? 10 : ((kt == NT - 2) ? 8 : 0);
                else             n = (kt < NT - 2) ? 8 : 4;   // s==3 here only reached for kt<=NT-2
                vmw(n);
                __builtin_amdgcn_sched_barrier(0);
                __builtin_amdgcn_s_barrier();
            }
        }
    }

    if (MODE == 0) {
        if (n0 < 512) {  // Q section: natural [32768][512]
#pragma unroll
            for (int m = 0; m < 8; ++m)
#pragma unroll
                for (int jn = 0; jn < 4; ++jn) {
                    const int col = n0 + wcn * 64 + jn * 16 + l16;
#pragma unroll
                    for (int i = 0; i < 4; ++i) {
                        const int row = m0 + wr * 128 + m * 16 + g * 4 + i;
                        Qo[(size_t)row * 512 + col] = f2bf(acc[m][jn][i]);
                    }
                }
        } else {         // K/V: transposed per head [b,h,d,n]
            u16* dst = (n0 < 1024) ? Kt : Vt;
#pragma unroll
            for (int m = 0; m < 8; ++m)
#pragma unroll
                for (int jn = 0; jn < 4; ++jn) {
                    const int col = (n0 + wcn * 64 + jn * 16 + l16) & 511;
                    const int h = col >> 6, d = col & 63;
                    const int rowb = m0 + wr * 128 + m * 16 + g * 4;
                    const int b = rowb >> 12, nn = rowb & 4095;
                    u16x4 pk;
#pragma unroll
                    for (int i = 0; i < 4; ++i) pk[i] = f2bf(acc[m][jn][i]);
                    *(u16x4*)(dst + ((size_t)((b * 8 + h) * 64 + d)) * 4096 + nn) = pk;
                }
        }
    } else {
#pragma unroll
        for (int m = 0; m < 8; ++m)
#pragma unroll
            for (int jn = 0; jn < 4; ++jn) {
                const int col = n0 + wcn * 64 + jn * 16 + l16;
                const float bb = bias[col];
#pragma unroll
                for (int i = 0; i < 4; ++i) {
                    const int row = m0 + wr * 128 + m * 16 + g * 4 + i;
                    Of[(size_t)row * N + col] = acc[m][jn][i] + bb;
                }
            }
    }
}

// ---------------- Linformer projections, split-K x4 (m97-style, unchanged) ----------------
__global__ __launch_bounds__(256) void k_proj(const u16* __restrict__ Et, const u16* __restrict__ Ft,
                                              const u16* __restrict__ Kt, const u16* __restrict__ Vt,
                                              float* __restrict__ pbuf) {
    __shared__ __attribute__((aligned(16))) char smem[24576];
    const int tid = threadIdx.x;
    const int lane = tid & 63, wid = tid >> 6;
    const int wr = wid >> 1, wc = wid & 1;
    const int g = lane >> 4, l16 = lane & 15;
    const int bid = blockIdx.x;
    const int sp = bid >> 8, rest = bid & 255;
    const int mt = rest & 1, which = (rest >> 1) & 1, bh = rest >> 2;
    const int h = bh & 7;
    const u16* Ap = (which ? Ft : Et) + (size_t)h * 256 * 4096 + (size_t)mt * 128 * 4096;
    const u16* Bp = (which ? Vt : Kt) + (size_t)bh * 64 * 4096;

    f32x4 acc[4][2] = {};

    const int kbeg = sp * 1024;
    for (int k0 = kbeg; k0 < kbeg + 1024; k0 += 64) {
#pragma unroll
        for (int c = 0; c < 4; ++c) {
            const int off = c * 4096 + tid * 16;
            const int row = off >> 7;
            const int sc = ((off >> 4) & 7) ^ (row & 7);
            gload16(Ap + (size_t)row * 4096 + (k0 + sc * 8), smem + off);
            if (c < 2)
                gload16(Bp + (size_t)row * 4096 + (k0 + sc * 8), smem + 16384 + off);
        }
        __syncthreads();
#pragma unroll
        for (int kk = 0; kk < 64; kk += 32) {
            bf16x8 av[4], bv[2];
#pragma unroll
            for (int m = 0; m < 4; ++m) {
                const int r = wr * 64 + m * 16 + l16;
                av[m] = *(const bf16x8*)(smem + r * 128 + ((kk * 2 + g * 16) ^ ((r & 7) << 4)));
            }
#pragma unroll
            for (int n = 0; n < 2; ++n) {
                const int r = wc * 32 + n * 16 + l16;
                bv[n] = *(const bf16x8*)(smem + 16384 + r * 128 + ((kk * 2 + g * 16) ^ ((r & 7) << 4)));
            }
            __builtin_amdgcn_s_setprio(1);
#pragma unroll
            for (int m = 0; m < 4; ++m)
#pragma unroll
                for (int n = 0; n < 2; ++n)
                    acc[m][n] = __builtin_amdgcn_mfma_f32_16x16x32_bf16(av[m], bv[n], acc[m][n], 0, 0, 0);
            __builtin_amdgcn_s_setprio(0);
        }
        __syncthreads();
    }

    float* pb = pbuf + ((size_t)(sp * 2 + which) * 64 + bh) * 16384;
    if (which == 0) {
#pragma unroll
        for (int m = 0; m < 4; ++m)
#pragma unroll
            for (int n = 0; n < 2; ++n) {
                const int d = wc * 32 + n * 16 + l16;
#pragma unroll
                for (int i = 0; i < 4; ++i) {
                    const int rg = mt * 128 + wr * 64 + m * 16 + g * 4 + i;
                    pb[rg * 64 + d] = acc[m][n][i];
                }
            }
    } else {
#pragma unroll
        for (int m = 0; m < 4; ++m)
#pragma unroll
            for (int n = 0; n < 2; ++n) {
                const int d = wc * 32 + n * 16 + l16;
                const int r4 = mt * 128 + wr * 64 + m * 16 + g * 4;
                *(f32x4*)(pb + d * 256 + r4) = acc[m][n];
            }
    }
}

__global__ __launch_bounds__(256) void k_preduce(const float* __restrict__ pbuf, u16* __restrict__ outkv) {
    const int o = ((int)blockIdx.x * 256 + (int)threadIdx.x) * 4;
    f32x4 s = *(const f32x4*)(pbuf + o);
    s += *(const f32x4*)(pbuf + 2097152 + o);
    s += *(const f32x4*)(pbuf + 4194304 + o);
    s += *(const f32x4*)(pbuf + 6291456 + o);
    u16x4 r;
#pragma unroll
    for (int i = 0; i < 4; ++i) r[i] = f2bf(s[i]);
    *(u16x4*)(outkv + o) = r;
}

// ---------------- fused scores + softmax + PV (unchanged) ----------------
__global__ __launch_bounds__(256) void k_flash(const u16* __restrict__ Q, const u16* __restrict__ kp,
                                               const u16* __restrict__ vpT, u16* __restrict__ ctx) {
    __shared__ __attribute__((aligned(16))) char smem[65536];
    const int tid = threadIdx.x;
    const int lane = tid & 63, w = tid >> 6;
    const int g = lane >> 4, l16 = lane & 15;
    const int bid = blockIdx.x;
    const int nt = bid & 63, bh = bid >> 6;
    const int b = bh >> 3, h = bh & 7;
    const int n0 = nt * 64;

#pragma unroll
    for (int c = 0; c < 8; ++c) {
        const int off = c * 4096 + tid * 16;
        {
            const int row = off >> 7;
            const int sc = ((off >> 4) & 7) ^ (row & 7);
            gload16(kp + (size_t)bh * 16384 + row * 64 + sc * 8, smem + off);
        }
        {
            const int row = off >> 9;
            const int sc = ((off >> 4) & 31) ^ (row & 7);
            gload16(vpT + (size_t)bh * 16384 + row * 256 + sc * 8, smem + 32768 + off);
        }
    }
    const size_t qbase = (size_t)(b * 4096 + n0 + w * 16 + l16) * 512 + h * 64 + g * 8;
    bf16x8 qf0 = *(const bf16x8*)(Q + qbase);
    bf16x8 qf1 = *(const bf16x8*)(Q + qbase + 32);
    __syncthreads();

    f32x4 s[16];
    __builtin_amdgcn_s_setprio(1);
#pragma unroll
    for (int rt = 0; rt < 16; ++rt) {
        const int r = rt * 16 + l16;
        const int sw = (r & 7) << 4;
        bf16x8 kv0 = *(const bf16x8*)(smem + r * 128 + ((g * 16) ^ sw));
        bf16x8 kv1 = *(const bf16x8*)(smem + r * 128 + ((64 + g * 16) ^ sw));
        f32x4 z = {0.f, 0.f, 0.f, 0.f};
        z = __builtin_amdgcn_mfma_f32_16x16x32_bf16(qf0, kv0, z, 0, 0, 0);
        z = __builtin_amdgcn_mfma_f32_16x16x32_bf16(qf1, kv1, z, 0, 0, 0);
        s[rt] = z;
    }
    __builtin_amdgcn_s_setprio(0);

    float mx[4] = {-1e30f, -1e30f, -1e30f, -1e30f};
#pragma unroll
    for (int rt = 0; rt < 16; ++rt)
#pragma unroll
        for (int i = 0; i < 4; ++i) {
            s[rt][i] *= 0.125f;
            mx[i] = fmaxf(mx[i], s[rt][i]);
        }
#pragma unroll
    for (int i = 0; i < 4; ++i) {
        mx[i] = fmaxf(mx[i], __shfl_xor(mx[i], 1));
        mx[i] = fmaxf(mx[i], __shfl_xor(mx[i], 2));
        mx[i] = fmaxf(mx[i], __shfl_xor(mx[i], 4));
        mx[i] = fmaxf(mx[i], __shfl_xor(mx[i], 8));
    }
    float sm[4] = {0.f, 0.f, 0.f, 0.f};
#pragma unroll
    for (int rt = 0; rt < 16; ++rt)
#pragma unroll
        for (int i = 0; i < 4; ++i) {
            float e = __expf(s[rt][i] - mx[i]);
            s[rt][i] = e;
            sm[i] += e;
        }
#pragma unroll
    for (int i = 0; i < 4; ++i) {
        sm[i] += __shfl_xor(sm[i], 1);
        sm[i] += __shfl_xor(sm[i], 2);
        sm[i] += __shfl_xor(sm[i], 4);
        sm[i] += __shfl_xor(sm[i], 8);
    }

    __syncthreads();

#pragma unroll
    for (int rt = 0; rt < 16; ++rt)
#pragma unroll
        for (int i = 0; i < 4; ++i) {
            const int nrow = g * 4 + i;
            const int byte = w * 8192 + nrow * 512 + ((rt * 32 + l16 * 2) ^ ((nrow & 7) << 4));
            *(u16*)(smem + byte) = f2bf(s[rt][i]);
        }
    bf16x8 af[8];
#pragma unroll
    for (int ks = 0; ks < 8; ++ks) {
        const int byte = w * 8192 + l16 * 512 + ((ks * 64 + g * 16) ^ ((l16 & 7) << 4));
        af[ks] = *(const bf16x8*)(smem + byte);
    }
    f32x4 o[4] = {};
    __builtin_amdgcn_s_setprio(1);
#pragma unroll
    for (int dt = 0; dt < 4; ++dt)
#pragma unroll
        for (int ks = 0; ks < 8; ++ks) {
            const int row = dt * 16 + l16;
            const int byte = 32768 + row * 512 + ((ks * 64 + g * 16) ^ ((row & 7) << 4));
            bf16x8 bv = *(const bf16x8*)(smem + byte);
            o[dt] = __builtin_amdgcn_mfma_f32_16x16x32_bf16(af[ks], bv, o[dt], 0, 0, 0);
        }
    __builtin_amdgcn_s_setprio(0);
    float rinv[4];
#pragma unroll
    for (int i = 0; i < 4; ++i) rinv[i] = 1.0f / sm[i];
#pragma unroll
    for (int dt = 0; dt < 4; ++dt)
#pragma unroll
        for (int i = 0; i < 4; ++i) {
            const int row = b * 4096 + n0 + w * 16 + g * 4 + i;
            const int col = h * 64 + dt * 16 + l16;
            ctx[(size_t)row * 512 + col] = f2bf(o[dt][i] * rinv[i]);
        }
}

// ---------------- host launch ----------------

extern "C" void kernel_launch(void* const* d_in, const int* in_sizes, int n_in,
                              void* d_out, int out_size, void* d_ws, size_t ws_size,
                              hipStream_t stream) {
    const float* x  = (const float*)d_in[0];
    const float* wq = (const float*)d_in[1];
    const float* wk = (const float*)d_in[2];
    const float* wv = (const float*)d_in[3];
    const float* E  = (const float*)d_in[4];
    const float* F  = (const float*)d_in[5];
    const float* wo = (const float*)d_in[6];
    const float* bo = (const float*)d_in[7];
    float* out = (float*)d_out;
    u16* ws = (u16*)d_ws;

    u16* xb    = ws;                 // x bf16 -> proj partials (f32) -> ctx
    u16* Qm    = ws + 16777216;
    u16* Kt    = ws + 33554432;      // [b,h,d,n]
    u16* Vt    = ws + 50331648;      // [b,h,d,n]
    u16* Et    = ws + 67108864;      // [h,r,n]
    u16* Ft    = ws + 75497472;
    u16* wcatT = ws + 83886080;
    u16* woT   = ws + 84672512;
    u16* kpB   = ws + 84934656;      // [bh,r,d] (kpB/vpT contiguous)
    u16* vpT   = ws + 85983232;      // [bh,d,r]
    float* pbuf = (float*)xb;
    u16* ctx   = xb;

    k_prep<<<20736, 256, 0, stream>>>(x, wq, wk, wv, wo, E, F, xb, wcatT, woT, Et, Ft);
    k_gemm8<0><<<768, 512, 0, stream>>>(xb, wcatT, Qm, Kt, Vt, nullptr, nullptr, 32768, 1536, 512);
    k_proj<<<1024, 256, 0, stream>>>(Et, Ft, Kt, Vt, pbuf);
    k_preduce<<<2048, 256, 0, stream>>>(pbuf, kpB);
    k_flash<<<4096, 256, 0, stream>>>(Qm, kpB, vpT, ctx);
    k_gemm8<1><<<256, 512, 0, stream>>>(ctx, woT, nullptr, nullptr, nullptr, out, bo, 32768, 512, 512);
}

// Round 5
// 368.236 us; speedup vs baseline: 1.0878x; 1.0309x over previous
//
#include <hip/hip_runtime.h>

typedef unsigned short u16;
typedef unsigned int   u32;
typedef __bf16 bf16x8 __attribute__((ext_vector_type(8)));
typedef float  f32x4  __attribute__((ext_vector_type(4)));
typedef u16    u16x4  __attribute__((ext_vector_type(4)));

#define DEV __device__ __forceinline__

DEV u16 f2bf(float f) {
    u32 u = __builtin_bit_cast(u32, f);
    u = (u + 0x7fffu + ((u >> 16) & 1u)) >> 16;
    return (u16)u;
}

DEV void gload16(const void* g, void* l) {
    __builtin_amdgcn_global_load_lds((const __attribute__((address_space(1))) u32*)g,
                                     (__attribute__((address_space(3))) u32*)l, 16, 0, 0);
}

DEV void vmw(int n) {  // counted vmcnt wait (literal required in asm)
    switch (n) {
        case 0:  asm volatile("s_waitcnt vmcnt(0)" ::: "memory"); break;
        case 4:  asm volatile("s_waitcnt vmcnt(4)" ::: "memory"); break;
        case 8:  asm volatile("s_waitcnt vmcnt(8)" ::: "memory"); break;
        default: asm volatile("s_waitcnt vmcnt(10)" ::: "memory"); break;
    }
}

// ---------------- merged prep: x->bf16 | E/F transpose | W transposes ----------------
__global__ __launch_bounds__(256) void k_prep(const float* __restrict__ x,
                                              const float* __restrict__ wq, const float* __restrict__ wk,
                                              const float* __restrict__ wv, const float* __restrict__ wo,
                                              const float* __restrict__ E, const float* __restrict__ F,
                                              u16* __restrict__ xb, u16* __restrict__ wcatT, u16* __restrict__ woT,
                                              u16* __restrict__ Et, u16* __restrict__ Ft) {
    __shared__ u16 tile[64][65];
    const int t = threadIdx.x;
    const int bid = blockIdx.x;
    if (bid < 16384) {                       // x fp32 -> bf16
        int i = (bid * 256 + t) * 4;
        float4 v = *(const float4*)(x + i);
        u16x4 o;
        o[0] = f2bf(v.x); o[1] = f2bf(v.y); o[2] = f2bf(v.z); o[3] = f2bf(v.w);
        *(u16x4*)(xb + i) = o;
    } else if (bid < 20480) {                // E/F [h][n][r] -> [h][r][n] bf16
        const int b2 = bid - 16384;
        const int rt = b2 & 3, ntl = (b2 >> 2) & 63, h = (b2 >> 8) & 7, which = b2 >> 11;
        const float* src = (which ? F : E) + (size_t)h * 4096 * 256;
        u16* dst = (which ? Ft : Et) + (size_t)h * 256 * 4096;
        const int n0 = ntl * 64, r0 = rt * 64;
#pragma unroll
        for (int it = 0; it < 16; ++it) {
            const int idx = t + it * 256;
            const int nl = idx >> 6, rl = idx & 63;
            tile[nl][rl] = f2bf(src[(size_t)(n0 + nl) * 256 + r0 + rl]);
        }
        __syncthreads();
#pragma unroll
        for (int it = 0; it < 16; ++it) {
            const int idx = t + it * 256;
            const int rl = idx >> 6, nl = idx & 63;
            dst[(size_t)(r0 + rl) * 4096 + n0 + nl] = tile[nl][rl];
        }
    } else {                                 // W transposes
        const int b2 = bid - 20480;
        const int mi = b2 >> 6, tix = b2 & 63;
        const int jt = tix & 7, kt = tix >> 3;
        const float* w = (mi == 0) ? wq : (mi == 1) ? wk : (mi == 2) ? wv : wo;
        u16* dst = (mi < 3) ? (wcatT + mi * 262144) : woT;
#pragma unroll
        for (int it = 0; it < 16; ++it) {
            const int idx = t + it * 256;
            const int kl = idx >> 6, jl = idx & 63;
            tile[kl][jl] = f2bf(w[(kt * 64 + kl) * 512 + jt * 64 + jl]);
        }
        __syncthreads();
#pragma unroll
        for (int it = 0; it < 16; ++it) {
            const int idx = t + it * 256;
            const int jl = idx >> 6, kl = idx & 63;
            dst[(size_t)(jt * 64 + jl) * 512 + kt * 64 + kl] = tile[kl][jl];
        }
    }
}

// ---------------- 8-phase 256x256 bf16 GEMM: C[M][N] = A[M][K] * B^T[N][K] ----------------
// 512 thr / 8 waves (2x4), per-wave C = 128x64. BK=64 split in 2 k-halves.
// LDS = 8 rotating 16KB half-tiles: A[4 slots] @0, B[4 slots] @64K.
// XCD banding: bm band FIXED per XCD (nbm/8 tiles), bn-fast within band ->
// concurrent L2 working set = ~6 bm-tiles of A (1.3MB) + all of B (<1.5MB).
template <int MODE>
__global__ __launch_bounds__(512, 2) void k_gemm8(const u16* __restrict__ A, const u16* __restrict__ Bm,
                                                  u16* __restrict__ Qo, u16* __restrict__ Kt, u16* __restrict__ Vt,
                                                  float* __restrict__ Of, const float* __restrict__ bias,
                                                  int M, int N, int K) {
    __shared__ __attribute__((aligned(16))) char smem[131072];
    const int tid = threadIdx.x;
    const int lane = tid & 63, w = tid >> 6;
    const int wr = w >> 2, wcn = w & 3;
    const int g = lane >> 4, l16 = lane & 15;
    const int nbm = M >> 8;
    const int bnc = N >> 8;
    const int bandw = nbm >> 3;               // bm tiles per XCD
    const int bid = (int)blockIdx.x;
    const int xcd = bid & 7, loc = bid >> 3;
    const int bm = xcd * bandw + loc / bnc;   // XCD-fixed band, bn-fast
    const int bn = loc % bnc;
    const int m0 = bm << 8, n0 = bn << 8;
    const int NT = K >> 6;

    auto stage_h = [&](int h) {
        const int ktile = h >> 2, ty = h & 3;
        const int kh = ty >> 1;
        const int isB = ty & 1;
        const int slot = (ktile * 2 + kh) & 3;
        const u16* src = isB ? Bm : A;
        const int r0 = isB ? n0 : m0;
        char* base = smem + isB * 65536 + slot * 16384;
#pragma unroll
        for (int j = 0; j < 2; ++j) {
            const int off = j * 8192 + tid * 16;
            const int row = off >> 6, c = (off >> 4) & 3;
            const int sc = c ^ ((row >> 1) & 3);        // pre-swizzled source -> swizzled LDS reads
            gload16(src + (size_t)(r0 + row) * K + ktile * 64 + kh * 32 + sc * 8, base + off);
        }
    };

    for (int h = 0; h < 6; ++h) stage_h(h);
    vmw(8);                                   // oldest 4 loads (h0,h1) landed
    __builtin_amdgcn_sched_barrier(0);
    __builtin_amdgcn_s_barrier();

    f32x4 acc[8][4] = {};
    bf16x8 av[8];
    for (int kt = 0; kt < NT; ++kt) {
#pragma unroll
        for (int s = 0; s < 4; ++s) {
            const int kh = s >> 1, nh = s & 1;
            const int slot = (kt * 2 + kh) & 3;
            char* abase = smem + slot * 16384;
            char* bbase = smem + 65536 + slot * 16384;
            if (nh == 0) {
#pragma unroll
                for (int m = 0; m < 8; ++m) {
                    const int row = wr * 128 + m * 16 + l16;
                    const int c = g ^ ((row >> 1) & 3);
                    av[m] = *(const bf16x8*)(abase + row * 64 + c * 16);
                }
            }
            bf16x8 bv[2];
#pragma unroll
            for (int n = 0; n < 2; ++n) {
                const int col = wcn * 64 + nh * 32 + n * 16 + l16;
                const int c = g ^ ((col >> 1) & 3);
                bv[n] = *(const bf16x8*)(bbase + col * 64 + c * 16);
            }
            const int hst = kt * 4 + s + 6;
            if (hst < NT * 4) stage_h(hst);
            __builtin_amdgcn_s_setprio(1);
#pragma unroll
            for (int m = 0; m < 8; ++m)
#pragma unroll
                for (int n = 0; n < 2; ++n)
                    acc[m][nh * 2 + n] = __builtin_amdgcn_mfma_f32_16x16x32_bf16(av[m], bv[n], acc[m][nh * 2 + n], 0, 0, 0);
            __builtin_amdgcn_s_setprio(0);
            const bool last = (kt == NT - 1) && (s == 3);
            if (!last) {
                int n;
                if (s == 0)      n = (kt < NT - 1) ? 10 : 4;
                else if (s == 1) n = (kt < NT - 1) ? 8 : 0;
                else if (s == 2) n = (kt < NT - 2) ? 10 : ((kt == NT - 2) ? 8 : 0);
                else             n = (kt < NT - 2) ? 8 : 4;   // s==3 here only reached for kt<=NT-2
                vmw(n);
                __builtin_amdgcn_sched_barrier(0);
                __builtin_amdgcn_s_barrier();
            }
        }
    }

    if (MODE == 0) {
        if (n0 < 512) {  // Q section: natural [32768][512]
#pragma unroll
            for (int m = 0; m < 8; ++m)
#pragma unroll
                for (int jn = 0; jn < 4; ++jn) {
                    const int col = n0 + wcn * 64 + jn * 16 + l16;
#pragma unroll
                    for (int i = 0; i < 4; ++i) {
                        const int row = m0 + wr * 128 + m * 16 + g * 4 + i;
                        Qo[(size_t)row * 512 + col] = f2bf(acc[m][jn][i]);
                    }
                }
        } else {         // K/V: transposed per head [b,h,d,n]
            u16* dst = (n0 < 1024) ? Kt : Vt;
#pragma unroll
            for (int m = 0; m < 8; ++m)
#pragma unroll
                for (int jn = 0; jn < 4; ++jn) {
                    const int col = (n0 + wcn * 64 + jn * 16 + l16) & 511;
                    const int h = col >> 6, d = col & 63;
                    const int rowb = m0 + wr * 128 + m * 16 + g * 4;
                    const int b = rowb >> 12, nn = rowb & 4095;
                    u16x4 pk;
#pragma unroll
                    for (int i = 0; i < 4; ++i) pk[i] = f2bf(acc[m][jn][i]);
                    *(u16x4*)(dst + ((size_t)((b * 8 + h) * 64 + d)) * 4096 + nn) = pk;
                }
        }
    } else {
#pragma unroll
        for (int m = 0; m < 8; ++m)
#pragma unroll
            for (int jn = 0; jn < 4; ++jn) {
                const int col = n0 + wcn * 64 + jn * 16 + l16;
                const float bb = bias[col];
#pragma unroll
                for (int i = 0; i < 4; ++i) {
                    const int row = m0 + wr * 128 + m * 16 + g * 4 + i;
                    Of[(size_t)row * N + col] = acc[m][jn][i] + bb;
                }
            }
    }
}

// ---------------- Linformer projections, split-K x4 (m97-style, unchanged) ----------------
__global__ __launch_bounds__(256) void k_proj(const u16* __restrict__ Et, const u16* __restrict__ Ft,
                                              const u16* __restrict__ Kt, const u16* __restrict__ Vt,
                                              float* __restrict__ pbuf) {
    __shared__ __attribute__((aligned(16))) char smem[24576];
    const int tid = threadIdx.x;
    const int lane = tid & 63, wid = tid >> 6;
    const int wr = wid >> 1, wc = wid & 1;
    const int g = lane >> 4, l16 = lane & 15;
    const int bid = blockIdx.x;
    const int sp = bid >> 8, rest = bid & 255;
    const int mt = rest & 1, which = (rest >> 1) & 1, bh = rest >> 2;
    const int h = bh & 7;
    const u16* Ap = (which ? Ft : Et) + (size_t)h * 256 * 4096 + (size_t)mt * 128 * 4096;
    const u16* Bp = (which ? Vt : Kt) + (size_t)bh * 64 * 4096;

    f32x4 acc[4][2] = {};

    const int kbeg = sp * 1024;
    for (int k0 = kbeg; k0 < kbeg + 1024; k0 += 64) {
#pragma unroll
        for (int c = 0; c < 4; ++c) {
            const int off = c * 4096 + tid * 16;
            const int row = off >> 7;
            const int sc = ((off >> 4) & 7) ^ (row & 7);
            gload16(Ap + (size_t)row * 4096 + (k0 + sc * 8), smem + off);
            if (c < 2)
                gload16(Bp + (size_t)row * 4096 + (k0 + sc * 8), smem + 16384 + off);
        }
        __syncthreads();
#pragma unroll
        for (int kk = 0; kk < 64; kk += 32) {
            bf16x8 av[4], bv[2];
#pragma unroll
            for (int m = 0; m < 4; ++m) {
                const int r = wr * 64 + m * 16 + l16;
                av[m] = *(const bf16x8*)(smem + r * 128 + ((kk * 2 + g * 16) ^ ((r & 7) << 4)));
            }
#pragma unroll
            for (int n = 0; n < 2; ++n) {
                const int r = wc * 32 + n * 16 + l16;
                bv[n] = *(const bf16x8*)(smem + 16384 + r * 128 + ((kk * 2 + g * 16) ^ ((r & 7) << 4)));
            }
            __builtin_amdgcn_s_setprio(1);
#pragma unroll
            for (int m = 0; m < 4; ++m)
#pragma unroll
                for (int n = 0; n < 2; ++n)
                    acc[m][n] = __builtin_amdgcn_mfma_f32_16x16x32_bf16(av[m], bv[n], acc[m][n], 0, 0, 0);
            __builtin_amdgcn_s_setprio(0);
        }
        __syncthreads();
    }

    float* pb = pbuf + ((size_t)(sp * 2 + which) * 64 + bh) * 16384;
    if (which == 0) {
#pragma unroll
        for (int m = 0; m < 4; ++m)
#pragma unroll
            for (int n = 0; n < 2; ++n) {
                const int d = wc * 32 + n * 16 + l16;
#pragma unroll
                for (int i = 0; i < 4; ++i) {
                    const int rg = mt * 128 + wr * 64 + m * 16 + g * 4 + i;
                    pb[rg * 64 + d] = acc[m][n][i];
                }
            }
    } else {
#pragma unroll
        for (int m = 0; m < 4; ++m)
#pragma unroll
            for (int n = 0; n < 2; ++n) {
                const int d = wc * 32 + n * 16 + l16;
                const int r4 = mt * 128 + wr * 64 + m * 16 + g * 4;
                *(f32x4*)(pb + d * 256 + r4) = acc[m][n];
            }
    }
}

__global__ __launch_bounds__(256) void k_preduce(const float* __restrict__ pbuf, u16* __restrict__ outkv) {
    const int o = ((int)blockIdx.x * 256 + (int)threadIdx.x) * 4;
    f32x4 s = *(const f32x4*)(pbuf + o);
    s += *(const f32x4*)(pbuf + 2097152 + o);
    s += *(const f32x4*)(pbuf + 4194304 + o);
    s += *(const f32x4*)(pbuf + 6291456 + o);
    u16x4 r;
#pragma unroll
    for (int i = 0; i < 4; ++i) r[i] = f2bf(s[i]);
    *(u16x4*)(outkv + o) = r;
}

// ---------------- fused scores + softmax + PV (unchanged) ----------------
__global__ __launch_bounds__(256) void k_flash(const u16* __restrict__ Q, const u16* __restrict__ kp,
                                               const u16* __restrict__ vpT, u16* __restrict__ ctx) {
    __shared__ __attribute__((aligned(16))) char smem[65536];
    const int tid = threadIdx.x;
    const int lane = tid & 63, w = tid >> 6;
    const int g = lane >> 4, l16 = lane & 15;
    const int bid = blockIdx.x;
    const int nt = bid & 63, bh = bid >> 6;
    const int b = bh >> 3, h = bh & 7;
    const int n0 = nt * 64;

#pragma unroll
    for (int c = 0; c < 8; ++c) {
        const int off = c * 4096 + tid * 16;
        {
            const int row = off >> 7;
            const int sc = ((off >> 4) & 7) ^ (row & 7);
            gload16(kp + (size_t)bh * 16384 + row * 64 + sc * 8, smem + off);
        }
        {
            const int row = off >> 9;
            const int sc = ((off >> 4) & 31) ^ (row & 7);
            gload16(vpT + (size_t)bh * 16384 + row * 256 + sc * 8, smem + 32768 + off);
        }
    }
    const size_t qbase = (size_t)(b * 4096 + n0 + w * 16 + l16) * 512 + h * 64 + g * 8;
    bf16x8 qf0 = *(const bf16x8*)(Q + qbase);
    bf16x8 qf1 = *(const bf16x8*)(Q + qbase + 32);
    __syncthreads();

    f32x4 s[16];
    __builtin_amdgcn_s_setprio(1);
#pragma unroll
    for (int rt = 0; rt < 16; ++rt) {
        const int r = rt * 16 + l16;
        const int sw = (r & 7) << 4;
        bf16x8 kv0 = *(const bf16x8*)(smem + r * 128 + ((g * 16) ^ sw));
        bf16x8 kv1 = *(const bf16x8*)(smem + r * 128 + ((64 + g * 16) ^ sw));
        f32x4 z = {0.f, 0.f, 0.f, 0.f};
        z = __builtin_amdgcn_mfma_f32_16x16x32_bf16(qf0, kv0, z, 0, 0, 0);
        z = __builtin_amdgcn_mfma_f32_16x16x32_bf16(qf1, kv1, z, 0, 0, 0);
        s[rt] = z;
    }
    __builtin_amdgcn_s_setprio(0);

    float mx[4] = {-1e30f, -1e30f, -1e30f, -1e30f};
#pragma unroll
    for (int rt = 0; rt < 16; ++rt)
#pragma unroll
        for (int i = 0; i < 4; ++i) {
            s[rt][i] *= 0.125f;
            mx[i] = fmaxf(mx[i], s[rt][i]);
        }
#pragma unroll
    for (int i = 0; i < 4; ++i) {
        mx[i] = fmaxf(mx[i], __shfl_xor(mx[i], 1));
        mx[i] = fmaxf(mx[i], __shfl_xor(mx[i], 2));
        mx[i] = fmaxf(mx[i], __shfl_xor(mx[i], 4));
        mx[i] = fmaxf(mx[i], __shfl_xor(mx[i], 8));
    }
    float sm[4] = {0.f, 0.f, 0.f, 0.f};
#pragma unroll
    for (int rt = 0; rt < 16; ++rt)
#pragma unroll
        for (int i = 0; i < 4; ++i) {
            float e = __expf(s[rt][i] - mx[i]);
            s[rt][i] = e;
            sm[i] += e;
        }
#pragma unroll
    for (int i = 0; i < 4; ++i) {
        sm[i] += __shfl_xor(sm[i], 1);
        sm[i] += __shfl_xor(sm[i], 2);
        sm[i] += __shfl_xor(sm[i], 4);
        sm[i] += __shfl_xor(sm[i], 8);
    }

    __syncthreads();

#pragma unroll
    for (int rt = 0; rt < 16; ++rt)
#pragma unroll
        for (int i = 0; i < 4; ++i) {
            const int nrow = g * 4 + i;
            const int byte = w * 8192 + nrow * 512 + ((rt * 32 + l16 * 2) ^ ((nrow & 7) << 4));
            *(u16*)(smem + byte) = f2bf(s[rt][i]);
        }
    bf16x8 af[8];
#pragma unroll
    for (int ks = 0; ks < 8; ++ks) {
        const int byte = w * 8192 + l16 * 512 + ((ks * 64 + g * 16) ^ ((l16 & 7) << 4));
        af[ks] = *(const bf16x8*)(smem + byte);
    }
    f32x4 o[4] = {};
    __builtin_amdgcn_s_setprio(1);
#pragma unroll
    for (int dt = 0; dt < 4; ++dt)
#pragma unroll
        for (int ks = 0; ks < 8; ++ks) {
            const int row = dt * 16 + l16;
            const int byte = 32768 + row * 512 + ((ks * 64 + g * 16) ^ ((row & 7) << 4));
            bf16x8 bv = *(const bf16x8*)(smem + byte);
            o[dt] = __builtin_amdgcn_mfma_f32_16x16x32_bf16(af[ks], bv, o[dt], 0, 0, 0);
        }
    __builtin_amdgcn_s_setprio(0);
    float rinv[4];
#pragma unroll
    for (int i = 0; i < 4; ++i) rinv[i] = 1.0f / sm[i];
#pragma unroll
    for (int dt = 0; dt < 4; ++dt)
#pragma unroll
        for (int i = 0; i < 4; ++i) {
            const int row = b * 4096 + n0 + w * 16 + g * 4 + i;
            const int col = h * 64 + dt * 16 + l16;
            ctx[(size_t)row * 512 + col] = f2bf(o[dt][i] * rinv[i]);
        }
}

// ---------------- host launch ----------------

extern "C" void kernel_launch(void* const* d_in, const int* in_sizes, int n_in,
                              void* d_out, int out_size, void* d_ws, size_t ws_size,
                              hipStream_t stream) {
    const float* x  = (const float*)d_in[0];
    const float* wq = (const float*)d_in[1];
    const float* wk = (const float*)d_in[2];
    const float* wv = (const float*)d_in[3];
    const float* E  = (const float*)d_in[4];
    const float* F  = (const float*)d_in[5];
    const float* wo = (const float*)d_in[6];
    const float* bo = (const float*)d_in[7];
    float* out = (float*)d_out;
    u16* ws = (u16*)d_ws;

    u16* xb    = ws;                 // x bf16 -> proj partials (f32) -> ctx
    u16* Qm    = ws + 16777216;
    u16* Kt    = ws + 33554432;      // [b,h,d,n]
    u16* Vt    = ws + 50331648;      // [b,h,d,n]
    u16* Et    = ws + 67108864;      // [h,r,n]
    u16* Ft    = ws + 75497472;
    u16* wcatT = ws + 83886080;
    u16* woT   = ws + 84672512;
    u16* kpB   = ws + 84934656;      // [bh,r,d] (kpB/vpT contiguous)
    u16* vpT   = ws + 85983232;      // [bh,d,r]
    float* pbuf = (float*)xb;
    u16* ctx   = xb;

    k_prep<<<20736, 256, 0, stream>>>(x, wq, wk, wv, wo, E, F, xb, wcatT, woT, Et, Ft);
    k_gemm8<0><<<768, 512, 0, stream>>>(xb, wcatT, Qm, Kt, Vt, nullptr, nullptr, 32768, 1536, 512);
    k_proj<<<1024, 256, 0, stream>>>(Et, Ft, Kt, Vt, pbuf);
    k_preduce<<<2048, 256, 0, stream>>>(pbuf, kpB);
    k_flash<<<4096, 256, 0, stream>>>(Qm, kpB, vpT, ctx);
    k_gemm8<1><<<256, 512, 0, stream>>>(ctx, woT, nullptr, nullptr, nullptr, out, bo, 32768, 512, 512);
}